// Round 3
// baseline (687.010 us; speedup 1.0000x reference)
//
#include <hip/hip_runtime.h>
#include <hip/hip_bf16.h>
#include <math.h>

// ResidualCache: out = softmax(top4(cos_sim(q, keys))) @ values
// [nrm] fp32->bf16 normalized rows   [score] bf16 MFMA GEMM + per-lane top-4 + LDS merge
// [final] wave-per-query: merge 32 cands -> fp32 exact rescore -> top-k -> softmax -> gather
// R3: SLICES=8 (grid 1024 -> 4 blocks/CU), end-of-block merge (32 cands/q), wave-final.

#define D_DIM 1024
#define SLICES 8
#define BQ 128
#define BK 128
#define BD 64
#define TLIST 4
#define CAND_PER_Q (SLICES * TLIST)   // 32 after in-block merge

typedef float f32x4 __attribute__((ext_vector_type(4)));
typedef short s16x8 __attribute__((ext_vector_type(8)));

typedef const __attribute__((address_space(1))) void* as1cv;
typedef __attribute__((address_space(3))) void* as3v;

__device__ __forceinline__ void gload_lds16(const void* g, void* l) {
    __builtin_amdgcn_global_load_lds((as1cv)g, (as3v)l, 16, 0, 0);
}

// round-to-nearest-even fp32 -> bf16 bits
__device__ __forceinline__ unsigned short f2bf(float x) {
    unsigned int u;
    __builtin_memcpy(&u, &x, 4);
    unsigned int r = (u + 0x7fffu + ((u >> 16) & 1u)) >> 16;
    return (unsigned short)r;
}

// ---------------- kernel 1: L2-normalize rows, emit bf16 + inv-norm ----------------
__global__ __launch_bounds__(256) void nrm_kernel(
    const float* __restrict__ q, const float* __restrict__ kmat,
    unsigned short* __restrict__ qn, unsigned short* __restrict__ kn,
    float* __restrict__ inv_qn, float* __restrict__ inv_kn, int B, int N) {
    int wid = threadIdx.x >> 6, lane = threadIdx.x & 63;
    int row = blockIdx.x * 4 + wid;
    if (row >= B + N) return;
    const float* src;
    unsigned short* dst;
    float* invp;
    if (row < B) {
        src = q + (size_t)row * D_DIM; dst = qn + (size_t)row * D_DIM; invp = inv_qn + row;
    } else {
        int r = row - B;
        src = kmat + (size_t)r * D_DIM; dst = kn + (size_t)r * D_DIM; invp = inv_kn + r;
    }
    float4 v[4];
    float ss = 0.f;
#pragma unroll
    for (int c = 0; c < 4; ++c) {
        v[c] = *(const float4*)(src + c * 256 + lane * 4);
        ss += v[c].x * v[c].x + v[c].y * v[c].y + v[c].z * v[c].z + v[c].w * v[c].w;
    }
#pragma unroll
    for (int m = 1; m < 64; m <<= 1) ss += __shfl_xor(ss, m, 64);
    float s = 1.0f / fmaxf(sqrtf(ss), 1e-12f);
    if (lane == 0) *invp = s;
#pragma unroll
    for (int c = 0; c < 4; ++c) {
        ushort4 o;
        o.x = f2bf(v[c].x * s); o.y = f2bf(v[c].y * s);
        o.z = f2bf(v[c].z * s); o.w = f2bf(v[c].w * s);
        *(ushort4*)(dst + c * 256 + lane * 4) = o;
    }
}

// ---------------- kernel 2: bf16 MFMA sim GEMM + per-lane top-4 + in-block merge ----------------
// Grid: (B/BQ)*SLICES blocks of 256. slice = blockIdx&7 (slice pinned to one XCD L2, 2 MB).
// Wave (wr,wc) covers keys [wr*64,+64) x queries [wc*64,+64) of the 128x128 tile.
// C/D frag (16x16x32): col(query)=lane&15, row(key)=(lane>>4)*4+j  [m89-verified]
__global__ __launch_bounds__(256, 4) void score_kernel(
    const unsigned short* __restrict__ qn, const unsigned short* __restrict__ kn,
    float* __restrict__ cand_s, int* __restrict__ cand_i, int B, int N) {
    // smem: tiles (Kt 16K + Qt 16K) aliased with merge arrays ([128][33] f32 + [128][33] i32)
    __shared__ __attribute__((aligned(16))) unsigned char smem[33792];
    unsigned short* Kt = (unsigned short*)smem;
    unsigned short* Qt = (unsigned short*)(smem + 16384);
    float* ms = (float*)smem;                 // [128][33] padded
    int* mi = (int*)(smem + 16896);           // [128][33] padded

    int bx = blockIdx.x;
    int qblk = bx >> 3, slice = bx & 7;
    int tid = threadIdx.x, wid = tid >> 6, lane = tid & 63;
    int wr = wid & 1, wc = wid >> 1;
    int slice_len = N / SLICES;           // 1024
    int kbase0 = slice * slice_len;
    int qbase = qblk * BQ;
    int lg = lane >> 4;

    float ts[4][TLIST];
    int   ti[4][TLIST];
#pragma unroll
    for (int cg = 0; cg < 4; ++cg)
#pragma unroll
        for (int t = 0; t < TLIST; ++t) { ts[cg][t] = -1e30f; ti[cg][t] = 0; }

    for (int kt = 0; kt < slice_len / BK; ++kt) {
        int kb = kbase0 + kt * BK;
        f32x4 acc[4][4];
#pragma unroll
        for (int a = 0; a < 4; ++a)
#pragma unroll
            for (int b = 0; b < 4; ++b) acc[a][b] = (f32x4){0.f, 0.f, 0.f, 0.f};

        for (int dc = 0; dc < D_DIM / BD; ++dc) {
            int db = dc * BD;
            // stage K tile (128x64 bf16) and Q tile (128x64) via global_load_lds w=16.
            // LDS dest linear; source col pre-swizzled: slot s of row r holds cols (s^(r&7))*8.
#pragma unroll
            for (int i = 0; i < 4; ++i) {
                int te = (i * 4 + wid) * 64 + lane;
                int r = te >> 3, sl = te & 7;
                int c = (sl ^ (r & 7)) * 8;
                gload_lds16(kn + (size_t)(kb + r) * D_DIM + db + c, &Kt[(i * 4 + wid) * 512]);
            }
#pragma unroll
            for (int i = 0; i < 4; ++i) {
                int te = (i * 4 + wid) * 64 + lane;
                int r = te >> 3, sl = te & 7;
                int c = (sl ^ (r & 7)) * 8;
                gload_lds16(qn + (size_t)(qbase + r) * D_DIM + db + c, &Qt[(i * 4 + wid) * 512]);
            }
            __syncthreads();
#pragma unroll
            for (int ks = 0; ks < 2; ++ks) {
                int kslot = ks * 4 + lg;   // 16B slot index in row
                s16x8 afr[4], bfr[4];
#pragma unroll
                for (int rb = 0; rb < 4; ++rb) {
                    int row = wr * 64 + rb * 16 + (lane & 15);
                    afr[rb] = *(const s16x8*)&Kt[row * BD + ((kslot ^ (row & 7)) * 8)];
                }
#pragma unroll
                for (int cg = 0; cg < 4; ++cg) {
                    int row = wc * 64 + cg * 16 + (lane & 15);
                    bfr[cg] = *(const s16x8*)&Qt[row * BD + ((kslot ^ (row & 7)) * 8)];
                }
#pragma unroll
                for (int rb = 0; rb < 4; ++rb)
#pragma unroll
                    for (int cg = 0; cg < 4; ++cg)
                        acc[rb][cg] = __builtin_amdgcn_mfma_f32_16x16x32_bf16(
                            afr[rb], bfr[cg], acc[rb][cg], 0, 0, 0);
            }
            __syncthreads();
        }
        // top-4 update: lane holds, per query-colgroup cg, 16 sims (4 rb x 4 j)
#pragma unroll
        for (int rb = 0; rb < 4; ++rb) {
#pragma unroll
            for (int j = 0; j < 4; ++j) {
                int key = kb + wr * 64 + rb * 16 + (lg << 2) + j;
#pragma unroll
                for (int cg = 0; cg < 4; ++cg) {
                    float s = acc[rb][cg][j];
                    if (s > ts[cg][TLIST - 1]) {
                        int id = key;
#pragma unroll
                        for (int t = 0; t < TLIST; ++t) {   // bubble-insert, keeps desc order
                            bool c = s > ts[cg][t];
                            float hi = c ? s : ts[cg][t];
                            float lo = c ? ts[cg][t] : s;
                            int ih = c ? id : ti[cg][t];
                            int il = c ? ti[cg][t] : id;
                            ts[cg][t] = hi; ti[cg][t] = ih; s = lo; id = il;
                        }
                    }
                }
            }
        }
    }

    // in-block merge: 32 per-subset lists -> top-4 per query for this slice.
    // (last dc-loop barrier guarantees no one still reads Kt/Qt; reuse as merge buf)
    __syncthreads();
#pragma unroll
    for (int cg = 0; cg < 4; ++cg) {
        int ql = wc * 64 + cg * 16 + (lane & 15);
        int slot = wr * 16 + lg * 4;
#pragma unroll
        for (int t = 0; t < TLIST; ++t) {
            ms[ql * 33 + slot + t] = ts[cg][t];
            mi[ql * 33 + slot + t] = ti[cg][t];
        }
    }
    __syncthreads();
    if (tid < BQ) {
        float bs[4] = {-1e30f, -1e30f, -1e30f, -1e30f};
        int bi4[4] = {0, 0, 0, 0};
#pragma unroll
        for (int s = 0; s < 32; ++s) {
            float v = ms[tid * 33 + s];
            int id = mi[tid * 33 + s];
            if (v > bs[3]) {
#pragma unroll
                for (int t = 0; t < 4; ++t) {
                    bool c = v > bs[t];
                    float hi = c ? v : bs[t];
                    float lo = c ? bs[t] : v;
                    int ih = c ? id : bi4[t];
                    int il = c ? bi4[t] : id;
                    bs[t] = hi; bi4[t] = ih; v = lo; id = il;
                }
            }
        }
        size_t base = (size_t)(qbase + tid) * CAND_PER_Q + slice * TLIST;
#pragma unroll
        for (int t = 0; t < 4; ++t) {
            cand_s[base + t] = bs[t];
            cand_i[base + t] = bi4[t];
        }
    }
}

// ---------------- kernel 3: wave-per-query finalize ----------------
// top-8 of 32 cands via shuffle-argmax -> fp32 exact rescore -> top-k (idx tiebreak)
// -> softmax -> weighted gather. No LDS, no __syncthreads.
__global__ __launch_bounds__(256) void final_kernel(
    const float* __restrict__ q, const float* __restrict__ kmat, const float* __restrict__ vmat,
    const float* __restrict__ inv_qn, const float* __restrict__ inv_kn,
    const float* __restrict__ cand_s, const int* __restrict__ cand_i,
    const int* __restrict__ kptr, float* __restrict__ out, int B, int N) {
    int wid = threadIdx.x >> 6, lane = threadIdx.x & 63;
    int qi = blockIdx.x * 4 + wid;
    int kk = *kptr;
    kk = kk < 1 ? 1 : (kk > 8 ? 8 : kk);

    size_t cb = (size_t)qi * CAND_PER_Q;
    float live = lane < 32 ? cand_s[cb + lane] : -1e30f;
    int ci = lane < 32 ? cand_i[cb + lane] : 0;

    // top-8 by bf16 score: 8x butterfly argmax (lane tiebreak -> deterministic)
    int sel[8];
#pragma unroll
    for (int it = 0; it < 8; ++it) {
        float v = live; int ln = lane;
#pragma unroll
        for (int m = 1; m < 64; m <<= 1) {
            float ov = __shfl_xor(v, m, 64);
            int oln = __shfl_xor(ln, m, 64);
            if (ov > v || (ov == v && oln < ln)) { v = ov; ln = oln; }
        }
        sel[it] = __shfl(ci, ln, 64);
        if (lane == ln) live = -1e30f;
    }

    // fp32 exact rescore: q row in regs (16 f32/lane)
    const float* qrow = q + (size_t)qi * D_DIM;
    float4 qv[4];
#pragma unroll
    for (int c = 0; c < 4; ++c) qv[c] = *(const float4*)(qrow + c * 256 + lane * 4);
    float invq = inv_qn[qi];
    float exsc[8];
#pragma unroll
    for (int c = 0; c < 8; ++c) {
        const float* krow = kmat + (size_t)sel[c] * D_DIM;
        float p = 0.f;
#pragma unroll
        for (int e = 0; e < 4; ++e) {
            float4 kv = *(const float4*)(krow + e * 256 + lane * 4);
            p += qv[e].x * kv.x + qv[e].y * kv.y + qv[e].z * kv.z + qv[e].w * kv.w;
        }
#pragma unroll
        for (int m = 1; m < 64; m <<= 1) p += __shfl_xor(p, m, 64);
        exsc[c] = p * invq * inv_kn[sel[c]];
    }

    // exact top-k among 8 (ties -> lower index, matches jax.lax.top_k); uniform on all lanes
    float wl[8]; int il[8]; bool used[8];
#pragma unroll
    for (int i = 0; i < 8; ++i) used[i] = false;
#pragma unroll
    for (int i = 0; i < 8; ++i) {
        int bj = 0; float bv = -1e30f; int bidx = 0x7fffffff;
#pragma unroll
        for (int j = 0; j < 8; ++j) {
            if (!used[j] && (exsc[j] > bv || (exsc[j] == bv && sel[j] < bidx))) {
                bv = exsc[j]; bidx = sel[j]; bj = j;
            }
        }
        used[bj] = true; wl[i] = bv; il[i] = bidx;
    }
    float m0 = wl[0], ssum = 0.f;
#pragma unroll
    for (int i = 0; i < 8; ++i) {
        wl[i] = (i < kk) ? __expf(wl[i] - m0) : 0.f;
        ssum += wl[i];
    }
    float rs = 1.0f / ssum;

    // gather: out = sum_i w_i * values[il_i]
    float4 o[4];
#pragma unroll
    for (int c = 0; c < 4; ++c) o[c] = (float4){0.f, 0.f, 0.f, 0.f};
#pragma unroll
    for (int i = 0; i < 8; ++i) {
        if (i < kk) {
            const float* vrow = vmat + (size_t)il[i] * D_DIM;
            float wi = wl[i] * rs;
#pragma unroll
            for (int c = 0; c < 4; ++c) {
                float4 vv = *(const float4*)(vrow + c * 256 + lane * 4);
                o[c].x += wi * vv.x; o[c].y += wi * vv.y;
                o[c].z += wi * vv.z; o[c].w += wi * vv.w;
            }
        }
    }
    float* orow = out + (size_t)qi * D_DIM;
#pragma unroll
    for (int c = 0; c < 4; ++c) *(float4*)(orow + c * 256 + lane * 4) = o[c];
}

extern "C" void kernel_launch(void* const* d_in, const int* in_sizes, int n_in,
                              void* d_out, int out_size, void* d_ws, size_t ws_size,
                              hipStream_t stream) {
    const float* q = (const float*)d_in[0];
    const float* kmat = (const float*)d_in[1];
    const float* vmat = (const float*)d_in[2];
    const int* kptr = (const int*)d_in[3];
    float* out = (float*)d_out;
    int B = in_sizes[0] / D_DIM;   // 16384
    int N = in_sizes[1] / D_DIM;   // 8192

    char* ws = (char*)d_ws;
    size_t off = 0;
    unsigned short* qn = (unsigned short*)(ws + off); off += (size_t)B * D_DIM * 2;
    unsigned short* kn = (unsigned short*)(ws + off); off += (size_t)N * D_DIM * 2;
    float* inv_qn = (float*)(ws + off); off += (size_t)B * 4;
    float* inv_kn = (float*)(ws + off); off += (size_t)N * 4;
    float* cand_s = (float*)(ws + off); off += (size_t)B * CAND_PER_Q * 4;
    int* cand_i = (int*)(ws + off); off += (size_t)B * CAND_PER_Q * 4;
    // total ~55 MB of d_ws

    int rows = B + N;
    nrm_kernel<<<dim3((rows + 3) / 4), dim3(256), 0, stream>>>(q, kmat, qn, kn, inv_qn, inv_kn, B, N);
    score_kernel<<<dim3((B / BQ) * SLICES), dim3(256), 0, stream>>>(qn, kn, cand_s, cand_i, B, N);
    final_kernel<<<dim3(B / 4), dim3(256), 0, stream>>>(q, kmat, vmat, inv_qn, inv_kn,
                                                        cand_s, cand_i, kptr, out, B, N);
}

// Round 4
// 682.980 us; speedup vs baseline: 1.0059x; 1.0059x over previous
//
#include <hip/hip_runtime.h>
#include <hip/hip_bf16.h>
#include <math.h>

// ResidualCache: out = softmax(top4(cos_sim(q, keys))) @ values
// [nrm] fp32->bf16 normalized rows   [score] bf16 MFMA GEMM + per-lane top-4 + LDS merge
// [final] wave-per-query: rank-select top-8 -> batched fp32 rescore -> top-k -> softmax -> gather
// R4: final_kernel rewritten for ILP (rank-select via independent shuffles; rescore with
//     8-wide independent accumulators + single combined butterfly). score/nrm untouched.

#define D_DIM 1024
#define SLICES 8
#define BQ 128
#define BK 128
#define BD 64
#define TLIST 4
#define CAND_PER_Q (SLICES * TLIST)   // 32 after in-block merge

typedef float f32x4 __attribute__((ext_vector_type(4)));
typedef short s16x8 __attribute__((ext_vector_type(8)));

typedef const __attribute__((address_space(1))) void* as1cv;
typedef __attribute__((address_space(3))) void* as3v;

__device__ __forceinline__ void gload_lds16(const void* g, void* l) {
    __builtin_amdgcn_global_load_lds((as1cv)g, (as3v)l, 16, 0, 0);
}

// round-to-nearest-even fp32 -> bf16 bits
__device__ __forceinline__ unsigned short f2bf(float x) {
    unsigned int u;
    __builtin_memcpy(&u, &x, 4);
    unsigned int r = (u + 0x7fffu + ((u >> 16) & 1u)) >> 16;
    return (unsigned short)r;
}

// ---------------- kernel 1: L2-normalize rows, emit bf16 + inv-norm ----------------
__global__ __launch_bounds__(256) void nrm_kernel(
    const float* __restrict__ q, const float* __restrict__ kmat,
    unsigned short* __restrict__ qn, unsigned short* __restrict__ kn,
    float* __restrict__ inv_qn, float* __restrict__ inv_kn, int B, int N) {
    int wid = threadIdx.x >> 6, lane = threadIdx.x & 63;
    int row = blockIdx.x * 4 + wid;
    if (row >= B + N) return;
    const float* src;
    unsigned short* dst;
    float* invp;
    if (row < B) {
        src = q + (size_t)row * D_DIM; dst = qn + (size_t)row * D_DIM; invp = inv_qn + row;
    } else {
        int r = row - B;
        src = kmat + (size_t)r * D_DIM; dst = kn + (size_t)r * D_DIM; invp = inv_kn + r;
    }
    float4 v[4];
    float ss = 0.f;
#pragma unroll
    for (int c = 0; c < 4; ++c) {
        v[c] = *(const float4*)(src + c * 256 + lane * 4);
        ss += v[c].x * v[c].x + v[c].y * v[c].y + v[c].z * v[c].z + v[c].w * v[c].w;
    }
#pragma unroll
    for (int m = 1; m < 64; m <<= 1) ss += __shfl_xor(ss, m, 64);
    float s = 1.0f / fmaxf(sqrtf(ss), 1e-12f);
    if (lane == 0) *invp = s;
#pragma unroll
    for (int c = 0; c < 4; ++c) {
        ushort4 o;
        o.x = f2bf(v[c].x * s); o.y = f2bf(v[c].y * s);
        o.z = f2bf(v[c].z * s); o.w = f2bf(v[c].w * s);
        *(ushort4*)(dst + c * 256 + lane * 4) = o;
    }
}

// ---------------- kernel 2: bf16 MFMA sim GEMM + per-lane top-4 + in-block merge ----------------
// Grid: (B/BQ)*SLICES blocks of 256. slice = blockIdx&7 (slice pinned to one XCD L2, 2 MB).
// Wave (wr,wc) covers keys [wr*64,+64) x queries [wc*64,+64) of the 128x128 tile.
// C/D frag (16x16x32): col(query)=lane&15, row(key)=(lane>>4)*4+j  [m89-verified]
__global__ __launch_bounds__(256, 4) void score_kernel(
    const unsigned short* __restrict__ qn, const unsigned short* __restrict__ kn,
    float* __restrict__ cand_s, int* __restrict__ cand_i, int B, int N) {
    // smem: tiles (Kt 16K + Qt 16K) aliased with merge arrays ([128][33] f32 + [128][33] i32)
    __shared__ __attribute__((aligned(16))) unsigned char smem[33792];
    unsigned short* Kt = (unsigned short*)smem;
    unsigned short* Qt = (unsigned short*)(smem + 16384);
    float* ms = (float*)smem;                 // [128][33] padded
    int* mi = (int*)(smem + 16896);           // [128][33] padded

    int bx = blockIdx.x;
    int qblk = bx >> 3, slice = bx & 7;
    int tid = threadIdx.x, wid = tid >> 6, lane = tid & 63;
    int wr = wid & 1, wc = wid >> 1;
    int slice_len = N / SLICES;           // 1024
    int kbase0 = slice * slice_len;
    int qbase = qblk * BQ;
    int lg = lane >> 4;

    float ts[4][TLIST];
    int   ti[4][TLIST];
#pragma unroll
    for (int cg = 0; cg < 4; ++cg)
#pragma unroll
        for (int t = 0; t < TLIST; ++t) { ts[cg][t] = -1e30f; ti[cg][t] = 0; }

    for (int kt = 0; kt < slice_len / BK; ++kt) {
        int kb = kbase0 + kt * BK;
        f32x4 acc[4][4];
#pragma unroll
        for (int a = 0; a < 4; ++a)
#pragma unroll
            for (int b = 0; b < 4; ++b) acc[a][b] = (f32x4){0.f, 0.f, 0.f, 0.f};

        for (int dc = 0; dc < D_DIM / BD; ++dc) {
            int db = dc * BD;
            // stage K tile (128x64 bf16) and Q tile (128x64) via global_load_lds w=16.
            // LDS dest linear; source col pre-swizzled: slot s of row r holds cols (s^(r&7))*8.
#pragma unroll
            for (int i = 0; i < 4; ++i) {
                int te = (i * 4 + wid) * 64 + lane;
                int r = te >> 3, sl = te & 7;
                int c = (sl ^ (r & 7)) * 8;
                gload_lds16(kn + (size_t)(kb + r) * D_DIM + db + c, &Kt[(i * 4 + wid) * 512]);
            }
#pragma unroll
            for (int i = 0; i < 4; ++i) {
                int te = (i * 4 + wid) * 64 + lane;
                int r = te >> 3, sl = te & 7;
                int c = (sl ^ (r & 7)) * 8;
                gload_lds16(qn + (size_t)(qbase + r) * D_DIM + db + c, &Qt[(i * 4 + wid) * 512]);
            }
            __syncthreads();
#pragma unroll
            for (int ks = 0; ks < 2; ++ks) {
                int kslot = ks * 4 + lg;   // 16B slot index in row
                s16x8 afr[4], bfr[4];
#pragma unroll
                for (int rb = 0; rb < 4; ++rb) {
                    int row = wr * 64 + rb * 16 + (lane & 15);
                    afr[rb] = *(const s16x8*)&Kt[row * BD + ((kslot ^ (row & 7)) * 8)];
                }
#pragma unroll
                for (int cg = 0; cg < 4; ++cg) {
                    int row = wc * 64 + cg * 16 + (lane & 15);
                    bfr[cg] = *(const s16x8*)&Qt[row * BD + ((kslot ^ (row & 7)) * 8)];
                }
#pragma unroll
                for (int rb = 0; rb < 4; ++rb)
#pragma unroll
                    for (int cg = 0; cg < 4; ++cg)
                        acc[rb][cg] = __builtin_amdgcn_mfma_f32_16x16x32_bf16(
                            afr[rb], bfr[cg], acc[rb][cg], 0, 0, 0);
            }
            __syncthreads();
        }
        // top-4 update: lane holds, per query-colgroup cg, 16 sims (4 rb x 4 j)
#pragma unroll
        for (int rb = 0; rb < 4; ++rb) {
#pragma unroll
            for (int j = 0; j < 4; ++j) {
                int key = kb + wr * 64 + rb * 16 + (lg << 2) + j;
#pragma unroll
                for (int cg = 0; cg < 4; ++cg) {
                    float s = acc[rb][cg][j];
                    if (s > ts[cg][TLIST - 1]) {
                        int id = key;
#pragma unroll
                        for (int t = 0; t < TLIST; ++t) {   // bubble-insert, keeps desc order
                            bool c = s > ts[cg][t];
                            float hi = c ? s : ts[cg][t];
                            float lo = c ? ts[cg][t] : s;
                            int ih = c ? id : ti[cg][t];
                            int il = c ? ti[cg][t] : id;
                            ts[cg][t] = hi; ti[cg][t] = ih; s = lo; id = il;
                        }
                    }
                }
            }
        }
    }

    // in-block merge: 32 per-subset lists -> top-4 per query for this slice.
    // (last dc-loop barrier guarantees no one still reads Kt/Qt; reuse as merge buf)
    __syncthreads();
#pragma unroll
    for (int cg = 0; cg < 4; ++cg) {
        int ql = wc * 64 + cg * 16 + (lane & 15);
        int slot = wr * 16 + lg * 4;
#pragma unroll
        for (int t = 0; t < TLIST; ++t) {
            ms[ql * 33 + slot + t] = ts[cg][t];
            mi[ql * 33 + slot + t] = ti[cg][t];
        }
    }
    __syncthreads();
    if (tid < BQ) {
        float bs[4] = {-1e30f, -1e30f, -1e30f, -1e30f};
        int bi4[4] = {0, 0, 0, 0};
#pragma unroll
        for (int s = 0; s < 32; ++s) {
            float v = ms[tid * 33 + s];
            int id = mi[tid * 33 + s];
            if (v > bs[3]) {
#pragma unroll
                for (int t = 0; t < 4; ++t) {
                    bool c = v > bs[t];
                    float hi = c ? v : bs[t];
                    float lo = c ? bs[t] : v;
                    int ih = c ? id : bi4[t];
                    int il = c ? bi4[t] : id;
                    bs[t] = hi; bi4[t] = ih; v = lo; id = il;
                }
            }
        }
        size_t base = (size_t)(qbase + tid) * CAND_PER_Q + slice * TLIST;
#pragma unroll
        for (int t = 0; t < 4; ++t) {
            cand_s[base + t] = bs[t];
            cand_i[base + t] = bi4[t];
        }
    }
}

// ---------------- kernel 3: wave-per-query finalize (ILP-restructured) ----------------
// rank-select top-8 (independent shuffles) -> batched fp32 rescore (8-wide ILP)
// -> exact top-k (idx tiebreak) -> softmax -> weighted gather. No LDS, no syncthreads.
__global__ __launch_bounds__(256) void final_kernel(
    const float* __restrict__ q, const float* __restrict__ kmat, const float* __restrict__ vmat,
    const float* __restrict__ inv_qn, const float* __restrict__ inv_kn,
    const float* __restrict__ cand_s, const int* __restrict__ cand_i,
    const int* __restrict__ kptr, float* __restrict__ out, int B, int N) {
    int wid = threadIdx.x >> 6, lane = threadIdx.x & 63;
    int qi = blockIdx.x * 4 + wid;
    int kk = *kptr;
    kk = kk < 1 ? 1 : (kk > 8 ? 8 : kk);

    size_t cb = (size_t)qi * CAND_PER_Q;
    float cs = lane < 32 ? cand_s[cb + lane] : -1e30f;
    int ci = lane < 32 ? cand_i[cb + lane] : 0x7fffffff;

    // rank of my candidate among all 32 (total order: score desc, index asc).
    // 32 independent broadcasts (compile-time lane index -> readlane), shallow chain.
    int rank = 0;
#pragma unroll
    for (int j = 0; j < 32; ++j) {
        float sj = __shfl(cs, j, 64);
        int ij = __shfl(ci, j, 64);
        rank += ((sj > cs) || (sj == cs && ij < ci)) ? 1 : 0;
    }
    // extract the 8 winners (ranks 0..7 are unique)
    int sel[8];
#pragma unroll
    for (int r = 0; r < 8; ++r) {
        unsigned long long m = __ballot(lane < 32 && rank == r);
        int ln = (int)__builtin_ctzll(m);
        sel[r] = __shfl(ci, ln, 64);
    }

    // batched fp32 exact rescore: q row in regs (16 f32/lane); all 8 candidates
    // accumulate in parallel (32 independent loads), one combined butterfly reduce.
    const float* qrow = q + (size_t)qi * D_DIM;
    float4 qv[4];
#pragma unroll
    for (int c = 0; c < 4; ++c) qv[c] = *(const float4*)(qrow + c * 256 + lane * 4);
    const float* kr[8];
#pragma unroll
    for (int r = 0; r < 8; ++r) kr[r] = kmat + (size_t)sel[r] * D_DIM;
    float p[8];
#pragma unroll
    for (int r = 0; r < 8; ++r) p[r] = 0.f;
#pragma unroll
    for (int e = 0; e < 4; ++e) {
#pragma unroll
        for (int r = 0; r < 8; ++r) {
            float4 kv = *(const float4*)(kr[r] + e * 256 + lane * 4);
            p[r] += qv[e].x * kv.x + qv[e].y * kv.y + qv[e].z * kv.z + qv[e].w * kv.w;
        }
    }
#pragma unroll
    for (int m = 1; m < 64; m <<= 1) {
#pragma unroll
        for (int r = 0; r < 8; ++r) p[r] += __shfl_xor(p[r], m, 64);
    }
    float invq = inv_qn[qi];
    float exsc[8];
#pragma unroll
    for (int r = 0; r < 8; ++r) exsc[r] = p[r] * invq * inv_kn[sel[r]];

    // exact top-k among 8 (ties -> lower index, matches jax.lax.top_k); uniform on all lanes
    float wl[8]; int il[8]; bool used[8];
#pragma unroll
    for (int i = 0; i < 8; ++i) used[i] = false;
#pragma unroll
    for (int i = 0; i < 8; ++i) {
        int bj = 0; float bv = -1e30f; int bidx = 0x7fffffff;
#pragma unroll
        for (int j = 0; j < 8; ++j) {
            if (!used[j] && (exsc[j] > bv || (exsc[j] == bv && sel[j] < bidx))) {
                bv = exsc[j]; bidx = sel[j]; bj = j;
            }
        }
        used[bj] = true; wl[i] = bv; il[i] = bidx;
    }
    float m0 = wl[0], ssum = 0.f;
#pragma unroll
    for (int i = 0; i < 8; ++i) {
        wl[i] = (i < kk) ? __expf(wl[i] - m0) : 0.f;
        ssum += wl[i];
    }
    float rs = 1.0f / ssum;

    // gather: out = sum_i w_i * values[il_i]  (independent loads, predicated-uniform)
    float4 o[4];
#pragma unroll
    for (int c = 0; c < 4; ++c) o[c] = (float4){0.f, 0.f, 0.f, 0.f};
#pragma unroll
    for (int i = 0; i < 8; ++i) {
        if (i < kk) {
            const float* vrow = vmat + (size_t)il[i] * D_DIM;
            float wi = wl[i] * rs;
#pragma unroll
            for (int c = 0; c < 4; ++c) {
                float4 vv = *(const float4*)(vrow + c * 256 + lane * 4);
                o[c].x += wi * vv.x; o[c].y += wi * vv.y;
                o[c].z += wi * vv.z; o[c].w += wi * vv.w;
            }
        }
    }
    float* orow = out + (size_t)qi * D_DIM;
#pragma unroll
    for (int c = 0; c < 4; ++c) *(float4*)(orow + c * 256 + lane * 4) = o[c];
}

extern "C" void kernel_launch(void* const* d_in, const int* in_sizes, int n_in,
                              void* d_out, int out_size, void* d_ws, size_t ws_size,
                              hipStream_t stream) {
    const float* q = (const float*)d_in[0];
    const float* kmat = (const float*)d_in[1];
    const float* vmat = (const float*)d_in[2];
    const int* kptr = (const int*)d_in[3];
    float* out = (float*)d_out;
    int B = in_sizes[0] / D_DIM;   // 16384
    int N = in_sizes[1] / D_DIM;   // 8192

    char* ws = (char*)d_ws;
    size_t off = 0;
    unsigned short* qn = (unsigned short*)(ws + off); off += (size_t)B * D_DIM * 2;
    unsigned short* kn = (unsigned short*)(ws + off); off += (size_t)N * D_DIM * 2;
    float* inv_qn = (float*)(ws + off); off += (size_t)B * 4;
    float* inv_kn = (float*)(ws + off); off += (size_t)N * 4;
    float* cand_s = (float*)(ws + off); off += (size_t)B * CAND_PER_Q * 4;
    int* cand_i = (int*)(ws + off); off += (size_t)B * CAND_PER_Q * 4;
    // total ~55 MB of d_ws

    int rows = B + N;
    nrm_kernel<<<dim3((rows + 3) / 4), dim3(256), 0, stream>>>(q, kmat, qn, kn, inv_qn, inv_kn, B, N);
    score_kernel<<<dim3((B / BQ) * SLICES), dim3(256), 0, stream>>>(qn, kn, cand_s, cand_i, B, N);
    final_kernel<<<dim3(B / 4), dim3(256), 0, stream>>>(q, kmat, vmat, inv_qn, inv_kn,
                                                        cand_s, cand_i, kptr, out, B, N);
}

// Round 5
// 651.106 us; speedup vs baseline: 1.0551x; 1.0490x over previous
//
#include <hip/hip_runtime.h>
#include <hip/hip_bf16.h>
#include <math.h>

// ResidualCache: out = softmax(top4(cos_sim(q, keys))) @ values
// [nrm] fp32->bf16 normalized rows   [score] bf16 MFMA GEMM (256x256 tile, dbuf) + top-4
// [final] wave-per-query: rank-select top-8 -> batched fp32 rescore -> top-k -> softmax -> gather
// R5: score tile 128x128 -> 256x256 (halves LDS-staging traffic 4GB->2GB), double-buffered
//     LDS with early-issued global_load_lds prefetch, setprio around MFMA, max-gated top-4 scan.

#define D_DIM 1024
#define SLICES 8
#define BQ 256
#define BK 256
#define BD 64
#define TLIST 4
#define CAND_PER_Q (SLICES * TLIST)   // 32 after in-block merge

typedef float f32x4 __attribute__((ext_vector_type(4)));
typedef short s16x8 __attribute__((ext_vector_type(8)));

typedef const __attribute__((address_space(1))) void* as1cv;
typedef __attribute__((address_space(3))) void* as3v;

__device__ __forceinline__ void gload_lds16(const void* g, void* l) {
    __builtin_amdgcn_global_load_lds((as1cv)g, (as3v)l, 16, 0, 0);
}

// round-to-nearest-even fp32 -> bf16 bits
__device__ __forceinline__ unsigned short f2bf(float x) {
    unsigned int u;
    __builtin_memcpy(&u, &x, 4);
    unsigned int r = (u + 0x7fffu + ((u >> 16) & 1u)) >> 16;
    return (unsigned short)r;
}

// ---------------- kernel 1: L2-normalize rows, emit bf16 + inv-norm ----------------
__global__ __launch_bounds__(256) void nrm_kernel(
    const float* __restrict__ q, const float* __restrict__ kmat,
    unsigned short* __restrict__ qn, unsigned short* __restrict__ kn,
    float* __restrict__ inv_qn, float* __restrict__ inv_kn, int B, int N) {
    int wid = threadIdx.x >> 6, lane = threadIdx.x & 63;
    int row = blockIdx.x * 4 + wid;
    if (row >= B + N) return;
    const float* src;
    unsigned short* dst;
    float* invp;
    if (row < B) {
        src = q + (size_t)row * D_DIM; dst = qn + (size_t)row * D_DIM; invp = inv_qn + row;
    } else {
        int r = row - B;
        src = kmat + (size_t)r * D_DIM; dst = kn + (size_t)r * D_DIM; invp = inv_kn + r;
    }
    float4 v[4];
    float ss = 0.f;
#pragma unroll
    for (int c = 0; c < 4; ++c) {
        v[c] = *(const float4*)(src + c * 256 + lane * 4);
        ss += v[c].x * v[c].x + v[c].y * v[c].y + v[c].z * v[c].z + v[c].w * v[c].w;
    }
#pragma unroll
    for (int m = 1; m < 64; m <<= 1) ss += __shfl_xor(ss, m, 64);
    float s = 1.0f / fmaxf(sqrtf(ss), 1e-12f);
    if (lane == 0) *invp = s;
#pragma unroll
    for (int c = 0; c < 4; ++c) {
        ushort4 o;
        o.x = f2bf(v[c].x * s); o.y = f2bf(v[c].y * s);
        o.z = f2bf(v[c].z * s); o.w = f2bf(v[c].w * s);
        *(ushort4*)(dst + c * 256 + lane * 4) = o;
    }
}

// ---------------- kernel 2: 256x256 bf16 MFMA tile + per-lane top-4 + in-block merge ----------------
// Grid: (B/BQ)*SLICES blocks of 512 (8 waves). slice = blockIdx&7 (pinned to one XCD's L2).
// Wave (wr,wc): keys [wr*128,+128) x queries [wc*64,+64). Per wave: acc[8][4] 16x16 frags.
// C/D frag (16x16x32): col(query)=lane&15, row(key)=(lane>>4)*4+j  [m89-verified]
// LDS 128 KiB: double-buffered Kt/Qt (256x64 bf16 each); staging via global_load_lds w=16
// with pre-swizzled source cols (slot s of row r holds cols (s^(r&7))*8), reads XOR back.
__global__ __launch_bounds__(512, 2) void score_kernel(
    const unsigned short* __restrict__ qn, const unsigned short* __restrict__ kn,
    float* __restrict__ cand_s, int* __restrict__ cand_i, int B, int N) {
    __shared__ __attribute__((aligned(16))) unsigned char smem[131072];
    // buf c: Kt at smem + c*65536, Qt at smem + 32768 + c*65536
    float* ms = (float*)smem;                  // merge overlay [256][33]
    int* mi = (int*)(smem + 33792);

    int bx = blockIdx.x;
    int qblk = bx >> 3, slice = bx & 7;
    int tid = threadIdx.x, wid = tid >> 6, lane = tid & 63;
    int wr = wid & 1, wc = wid >> 1;           // wr: key half, wc: query quarter
    int lg = lane >> 4, l15 = lane & 15;
    int slice_len = N / SLICES;                // 1024
    int kbase0 = slice * slice_len;
    int qbase = qblk * BQ;

    float ts[4][TLIST];
    int   ti[4][TLIST];
#pragma unroll
    for (int cg = 0; cg < 4; ++cg)
#pragma unroll
        for (int t = 0; t < TLIST; ++t) { ts[cg][t] = -1e30f; ti[cg][t] = 0; }

    // stage one 256x64 K-tile + 256x64 Q-tile into buffer c (8 x global_load_lds_dwordx4)
    auto STAGE = [&](int c, int kb, int db) {
        unsigned short* KtD = (unsigned short*)(smem + c * 65536);
        unsigned short* QtD = (unsigned short*)(smem + 32768 + c * 65536);
#pragma unroll
        for (int i = 0; i < 4; ++i) {
            int te = i * 512 + tid;
            int r = te >> 3, sl = te & 7;
            int col = (sl ^ (r & 7)) * 8;
            gload_lds16(kn + (size_t)(kb + r) * D_DIM + db + col, &KtD[i * 4096 + wid * 512]);
        }
#pragma unroll
        for (int i = 0; i < 4; ++i) {
            int te = i * 512 + tid;
            int r = te >> 3, sl = te & 7;
            int col = (sl ^ (r & 7)) * 8;
            gload_lds16(qn + (size_t)(qbase + r) * D_DIM + db + col, &QtD[i * 4096 + wid * 512]);
        }
    };

    for (int kt = 0; kt < slice_len / BK; ++kt) {   // 4 key-tiles per slice
        int kb = kbase0 + kt * BK;
        f32x4 acc[8][4];
#pragma unroll
        for (int a = 0; a < 8; ++a)
#pragma unroll
            for (int b = 0; b < 4; ++b) acc[a][b] = (f32x4){0.f, 0.f, 0.f, 0.f};

        STAGE(0, kb, 0);
        __syncthreads();                        // drains vmcnt, buf0 ready
        int cur = 0;
        for (int dc = 0; dc < D_DIM / BD; ++dc) {   // 16 D-chunks
            if (dc + 1 < D_DIM / BD) STAGE(cur ^ 1, kb, (dc + 1) * BD);   // prefetch, in flight over MFMA
            const unsigned short* KtC = (const unsigned short*)(smem + cur * 65536);
            const unsigned short* QtC = (const unsigned short*)(smem + 32768 + cur * 65536);
#pragma unroll
            for (int ks = 0; ks < 2; ++ks) {
                int kslot = ks * 4 + lg;        // 16B slot in 128B row
                s16x8 afr[8], bfr[4];
#pragma unroll
                for (int rb = 0; rb < 8; ++rb) {
                    int row = wr * 128 + rb * 16 + l15;
                    afr[rb] = *(const s16x8*)&KtC[row * BD + ((kslot ^ (row & 7)) * 8)];
                }
#pragma unroll
                for (int cg = 0; cg < 4; ++cg) {
                    int row = wc * 64 + cg * 16 + l15;
                    bfr[cg] = *(const s16x8*)&QtC[row * BD + ((kslot ^ (row & 7)) * 8)];
                }
                __builtin_amdgcn_s_setprio(1);
#pragma unroll
                for (int rb = 0; rb < 8; ++rb)
#pragma unroll
                    for (int cg = 0; cg < 4; ++cg)
                        acc[rb][cg] = __builtin_amdgcn_mfma_f32_16x16x32_bf16(
                            afr[rb], bfr[cg], acc[rb][cg], 0, 0, 0);
                __builtin_amdgcn_s_setprio(0);
            }
            __syncthreads();                    // drains prefetch vmcnt + lgkm, flip
            cur ^= 1;
        }
        // gated top-4 update: per cg, 32 sims (8 rb x 4 j); skip scan if none can enter
#pragma unroll
        for (int cg = 0; cg < 4; ++cg) {
            float mx = acc[0][cg][0];
#pragma unroll
            for (int rb = 0; rb < 8; ++rb)
#pragma unroll
                for (int j = 0; j < 4; ++j) mx = fmaxf(mx, acc[rb][cg][j]);
            if (__any(mx > ts[cg][TLIST - 1])) {
#pragma unroll
                for (int rb = 0; rb < 8; ++rb) {
#pragma unroll
                    for (int j = 0; j < 4; ++j) {
                        float s = acc[rb][cg][j];
                        if (s > ts[cg][TLIST - 1]) {
                            int id = kb + wr * 128 + rb * 16 + (lg << 2) + j;
#pragma unroll
                            for (int t = 0; t < TLIST; ++t) {   // bubble-insert, desc order
                                bool c = s > ts[cg][t];
                                float hi = c ? s : ts[cg][t];
                                float lo = c ? ts[cg][t] : s;
                                int ih = c ? id : ti[cg][t];
                                int il = c ? ti[cg][t] : id;
                                ts[cg][t] = hi; ti[cg][t] = ih; s = lo; id = il;
                            }
                        }
                    }
                }
            }
        }
    }

    // in-block merge: 32 per-subset lists -> top-4 per query for this slice.
    // (last dc barrier passed; scan is reg-only -> safe to overlay merge arrays on tiles)
    __syncthreads();
#pragma unroll
    for (int cg = 0; cg < 4; ++cg) {
        int ql = wc * 64 + cg * 16 + l15;
        int slot = wr * 16 + lg * 4;
#pragma unroll
        for (int t = 0; t < TLIST; ++t) {
            ms[ql * 33 + slot + t] = ts[cg][t];
            mi[ql * 33 + slot + t] = ti[cg][t];
        }
    }
    __syncthreads();
    if (tid < BQ) {
        float bs[4] = {-1e30f, -1e30f, -1e30f, -1e30f};
        int bi4[4] = {0, 0, 0, 0};
#pragma unroll
        for (int s = 0; s < 32; ++s) {
            float v = ms[tid * 33 + s];
            int id = mi[tid * 33 + s];
            if (v > bs[3]) {
#pragma unroll
                for (int t = 0; t < 4; ++t) {
                    bool c = v > bs[t];
                    float hi = c ? v : bs[t];
                    float lo = c ? bs[t] : v;
                    int ih = c ? id : bi4[t];
                    int il = c ? bi4[t] : id;
                    bs[t] = hi; bi4[t] = ih; v = lo; id = il;
                }
            }
        }
        size_t base = (size_t)(qbase + tid) * CAND_PER_Q + slice * TLIST;
#pragma unroll
        for (int t = 0; t < 4; ++t) {
            cand_s[base + t] = bs[t];
            cand_i[base + t] = bi4[t];
        }
    }
}

// ---------------- kernel 3: wave-per-query finalize (ILP-restructured) ----------------
// rank-select top-8 (independent shuffles) -> batched fp32 rescore (8-wide ILP)
// -> exact top-k (idx tiebreak) -> softmax -> weighted gather. No LDS, no syncthreads.
__global__ __launch_bounds__(256) void final_kernel(
    const float* __restrict__ q, const float* __restrict__ kmat, const float* __restrict__ vmat,
    const float* __restrict__ inv_qn, const float* __restrict__ inv_kn,
    const float* __restrict__ cand_s, const int* __restrict__ cand_i,
    const int* __restrict__ kptr, float* __restrict__ out, int B, int N) {
    int wid = threadIdx.x >> 6, lane = threadIdx.x & 63;
    int qi = blockIdx.x * 4 + wid;
    int kk = *kptr;
    kk = kk < 1 ? 1 : (kk > 8 ? 8 : kk);

    size_t cb = (size_t)qi * CAND_PER_Q;
    float cs = lane < 32 ? cand_s[cb + lane] : -1e30f;
    int ci = lane < 32 ? cand_i[cb + lane] : 0x7fffffff;

    // rank of my candidate among all 32 (total order: score desc, index asc)
    int rank = 0;
#pragma unroll
    for (int j = 0; j < 32; ++j) {
        float sj = __shfl(cs, j, 64);
        int ij = __shfl(ci, j, 64);
        rank += ((sj > cs) || (sj == cs && ij < ci)) ? 1 : 0;
    }
    // extract the 8 winners (ranks 0..7 are unique)
    int sel[8];
#pragma unroll
    for (int r = 0; r < 8; ++r) {
        unsigned long long m = __ballot(lane < 32 && rank == r);
        int ln = (int)__builtin_ctzll(m);
        sel[r] = __shfl(ci, ln, 64);
    }

    // batched fp32 exact rescore: q row in regs; 8 candidates accumulate in parallel
    const float* qrow = q + (size_t)qi * D_DIM;
    float4 qv[4];
#pragma unroll
    for (int c = 0; c < 4; ++c) qv[c] = *(const float4*)(qrow + c * 256 + lane * 4);
    const float* kr[8];
#pragma unroll
    for (int r = 0; r < 8; ++r) kr[r] = kmat + (size_t)sel[r] * D_DIM;
    float p[8];
#pragma unroll
    for (int r = 0; r < 8; ++r) p[r] = 0.f;
#pragma unroll
    for (int e = 0; e < 4; ++e) {
#pragma unroll
        for (int r = 0; r < 8; ++r) {
            float4 kv = *(const float4*)(kr[r] + e * 256 + lane * 4);
            p[r] += qv[e].x * kv.x + qv[e].y * kv.y + qv[e].z * kv.z + qv[e].w * kv.w;
        }
    }
#pragma unroll
    for (int m = 1; m < 64; m <<= 1) {
#pragma unroll
        for (int r = 0; r < 8; ++r) p[r] += __shfl_xor(p[r], m, 64);
    }
    float invq = inv_qn[qi];
    float exsc[8];
#pragma unroll
    for (int r = 0; r < 8; ++r) exsc[r] = p[r] * invq * inv_kn[sel[r]];

    // exact top-k among 8 (ties -> lower index, matches jax.lax.top_k); uniform on all lanes
    float wl[8]; int il[8]; bool used[8];
#pragma unroll
    for (int i = 0; i < 8; ++i) used[i] = false;
#pragma unroll
    for (int i = 0; i < 8; ++i) {
        int bj = 0; float bv = -1e30f; int bidx = 0x7fffffff;
#pragma unroll
        for (int j = 0; j < 8; ++j) {
            if (!used[j] && (exsc[j] > bv || (exsc[j] == bv && sel[j] < bidx))) {
                bv = exsc[j]; bidx = sel[j]; bj = j;
            }
        }
        used[bj] = true; wl[i] = bv; il[i] = bidx;
    }
    float m0 = wl[0], ssum = 0.f;
#pragma unroll
    for (int i = 0; i < 8; ++i) {
        wl[i] = (i < kk) ? __expf(wl[i] - m0) : 0.f;
        ssum += wl[i];
    }
    float rs = 1.0f / ssum;

    // gather: out = sum_i w_i * values[il_i]
    float4 o[4];
#pragma unroll
    for (int c = 0; c < 4; ++c) o[c] = (float4){0.f, 0.f, 0.f, 0.f};
#pragma unroll
    for (int i = 0; i < 8; ++i) {
        if (i < kk) {
            const float* vrow = vmat + (size_t)il[i] * D_DIM;
            float wi = wl[i] * rs;
#pragma unroll
            for (int c = 0; c < 4; ++c) {
                float4 vv = *(const float4*)(vrow + c * 256 + lane * 4);
                o[c].x += wi * vv.x; o[c].y += wi * vv.y;
                o[c].z += wi * vv.z; o[c].w += wi * vv.w;
            }
        }
    }
    float* orow = out + (size_t)qi * D_DIM;
#pragma unroll
    for (int c = 0; c < 4; ++c) *(float4*)(orow + c * 256 + lane * 4) = o[c];
}

extern "C" void kernel_launch(void* const* d_in, const int* in_sizes, int n_in,
                              void* d_out, int out_size, void* d_ws, size_t ws_size,
                              hipStream_t stream) {
    const float* q = (const float*)d_in[0];
    const float* kmat = (const float*)d_in[1];
    const float* vmat = (const float*)d_in[2];
    const int* kptr = (const int*)d_in[3];
    float* out = (float*)d_out;
    int B = in_sizes[0] / D_DIM;   // 16384
    int N = in_sizes[1] / D_DIM;   // 8192

    char* ws = (char*)d_ws;
    size_t off = 0;
    unsigned short* qn = (unsigned short*)(ws + off); off += (size_t)B * D_DIM * 2;
    unsigned short* kn = (unsigned short*)(ws + off); off += (size_t)N * D_DIM * 2;
    float* inv_qn = (float*)(ws + off); off += (size_t)B * 4;
    float* inv_kn = (float*)(ws + off); off += (size_t)N * 4;
    float* cand_s = (float*)(ws + off); off += (size_t)B * CAND_PER_Q * 4;
    int* cand_i = (int*)(ws + off); off += (size_t)B * CAND_PER_Q * 4;
    // total ~55 MB of d_ws

    int rows = B + N;
    nrm_kernel<<<dim3((rows + 3) / 4), dim3(256), 0, stream>>>(q, kmat, qn, kn, inv_qn, inv_kn, B, N);
    score_kernel<<<dim3((B / BQ) * SLICES), dim3(512), 0, stream>>>(qn, kn, cand_s, cand_i, B, N);
    final_kernel<<<dim3(B / 4), dim3(256), 0, stream>>>(q, kmat, vmat, inv_qn, inv_kn,
                                                        cand_s, cand_i, kptr, out, B, N);
}